// Round 2
// baseline (120.330 us; speedup 1.0000x reference)
//
#include <hip/hip_runtime.h>
#include <hip/hip_bf16.h>

// out[b,i] = sum_{j<=i} x[b,j] * kernel[i-j]   (causal Toeplitz matmul)
// M=2048, N=K=4096. f32 in/out, bf16 MFMA compute.
//
// R7: XCD-affine m-panel mapping. R6 (stage-early single-barrier pipeline) cut
// the gemm 52.5 -> ~42 us. Remaining gap vs the ~21 us LDS-port floor is
// operand delivery: A panels (1 MB bf16 each) are re-read by up to 32
// column-tile blocks (~277 MB total); the old boustrophedon mapping spread a
// panel's readers across XCDs and switched panel sets between dispatch halves,
// so A was served from L3 (~450-600 cyc latency, ~6.5 TB/s demand). Now each
// XCD owns exactly 2 m-panels for the whole kernel (x=b&7, j=b>>3,
// mt=x+8*(j&1), ct=31-(j>>1)): 2 MB working set -> L2-resident, L2-class
// latency on all stage loads. Balance preserved (every XCD sees each ct twice,
// heavy-first descending). Plus s_setprio(1) around the MFMA clusters.

typedef unsigned short u16;
typedef __attribute__((ext_vector_type(8))) short  bf16x8;
typedef __attribute__((ext_vector_type(8))) unsigned short u16x8;
typedef __attribute__((ext_vector_type(4))) float  f32x4;

#define KDIM 4096
#define NDIM 4096
#define MDIM 2048
#define KREV_STRIDE 4608                    // elems per shifted copy
#define KREV_BYTES  (8 * KREV_STRIDE * 2)   // 73728
#define BSTRIDE 456                         // LDS B copy stride (elems); reads need [8,399)
#define BBUF    (8 * BSTRIDE)               // 3648 elems per B buffer

static __device__ inline u16 f2bf(float f) {
  unsigned u = __builtin_bit_cast(unsigned, f);
  unsigned r = u + 0x7FFFu + ((u >> 16) & 1u);
  return (u16)(r >> 16);
}

static __device__ inline void async_copy16(const void* g, void* l) {
  __builtin_amdgcn_global_load_lds((const __attribute__((address_space(1))) void*)g,
                                   (__attribute__((address_space(3))) void*)l,
                                   16, 0, 0);
}

// Fused prep: blocks [0, conv_blocks) convert x->bf16; last 18 blocks build
// 8 shifted krev copies. krevs[a][u] = krev_logical[u+a-8];
// krev_logical[t] = kern[4095-t] for t in [0,4096) else 0.
__global__ __launch_bounds__(256) void prep(const float* __restrict__ x,
                                            const float* __restrict__ kern,
                                            u16* __restrict__ xb,
                                            u16* __restrict__ krevs,
                                            int conv_blocks) {
  int kb = (int)blockIdx.x - conv_blocks;
  if (kb >= 0) {
    int u = kb * 256 + threadIdx.x;
    for (int a = 0; a < 8; ++a) {
      int t = u + a - 8;
      u16 v = 0;
      if (t >= 0 && t <= 4095) v = f2bf(kern[4095 - t]);
      krevs[a * KREV_STRIDE + u] = v;
    }
  } else {
    size_t i = ((size_t)blockIdx.x * 256 + threadIdx.x) * 8;
    const f32x4* p = (const f32x4*)(x + i);
    f32x4 v0 = p[0], v1 = p[1];
    u16x8 r;
    r[0] = f2bf(v0[0]); r[1] = f2bf(v0[1]); r[2] = f2bf(v0[2]); r[3] = f2bf(v0[3]);
    r[4] = f2bf(v1[0]); r[5] = f2bf(v1[1]); r[6] = f2bf(v1[2]); r[7] = f2bf(v1[3]);
    *(u16x8*)(xb + i) = r;
  }
}

template <bool CONV>
__global__ __launch_bounds__(512, 4) void toeplitz_gemm(const void* __restrict__ Av,
                                                        const u16* __restrict__ krevs,
                                                        float* __restrict__ out) {
  // layout: A [2 groups][2 bufs][128*64] = 32768 elems (65536 B),
  // B [2 bufs][8*456] = 7296 elems (14592 B). total 80128 B -> 2 blocks/CU.
  // Epilogue overlays (needs 36864 B).
  __shared__ __align__(16) char smem_raw[80128];
  u16*   A_all = (u16*)smem_raw;              // 4 x 8192 elems: (g<<1|buf)
  u16*   B_all = (u16*)(smem_raw + 65536);    // 2 x 3648 elems
  f32x4* ep    = (f32x4*)smem_raw;            // epilogue overlay, 9 f32x4 per slot

  const int tid  = threadIdx.x;
  const int w    = tid >> 6;        // 0..7
  const int g    = w >> 2;          // K-group 0..1
  const int wl   = w & 3;           // wave-in-group
  const int lane = tid & 63;
  const int lane16 = lane & 15;
  const int quad   = lane >> 4;
  const int wm = wl >> 1;
  const int wn = wl & 1;

  // XCD-affine mapping: XCD x = b&7 owns m-panels {x, x+8} only (2 MB bf16 ->
  // L2-resident for the whole kernel). ct descends (heavy first) so early
  // finishers pick up the heaviest remaining light block; each XCD sees every
  // ct exactly twice -> per-XCD step totals identical.
  const int b  = (int)blockIdx.x;
  const int x_ = b & 7;
  const int jj = b >> 3;                  // 0..63 within XCD
  const int mt = x_ + 8 * (jj & 1);       // m-panel 0..15
  const int ct = 31 - (jj >> 1);          // column tile, heavy first
  const int n0 = ct * 128;
  const int m0 = mt * 128;
  const int W  = 3968 - n0;               // B window base for chunk 0

  // B frag: elem j = krev_logical[s0 + k], s0 = 4095-n_g+quad*8; chunk c holds
  // krev_logical[W + c*256 + u + a - 8] at copy a elem u (u in [0,448)).
  int boff[4];
  for (int fn = 0; fn < 4; ++fn) {
    int n_g = n0 + wn * 64 + fn * 16 + lane16;
    int s0  = 4095 - n_g + quad * 8;
    int a   = s0 & 7;
    boff[fn] = a * BSTRIDE + (s0 - a + 8 - W);
  }

  f32x4 acc[4][4] = {};
  const int srow8 = lane >> 3;
  const int ssrc  = ((lane & 7) ^ srow8) * 8;   // XOR source swizzle (16B chunks)

  const u16*  xb = (const u16*)Av;
  const float* xf = (const float*)Av;

  auto stageA = [&](int t) {
    const int k0 = t * 128 + g * 64;
    u16* A_dst = A_all + (((g << 1) | (t & 1)) << 13);   // *8192
    if constexpr (CONV) {
      int j    = tid & 255;                // 256 threads per group
      int row  = j >> 1;
      int lh   = j & 1;
      for (int lc = 0; lc < 4; ++lc) {
        int l = lh * 4 + lc;
        int p = l ^ (row & 7);
        const f32x4* px = (const f32x4*)(xf + (size_t)(m0 + row) * KDIM + k0 + l * 8);
        f32x4 v0 = px[0], v1 = px[1];
        u16x8 r;
        r[0]=f2bf(v0[0]); r[1]=f2bf(v0[1]); r[2]=f2bf(v0[2]); r[3]=f2bf(v0[3]);
        r[4]=f2bf(v1[0]); r[5]=f2bf(v1[1]); r[6]=f2bf(v1[2]); r[7]=f2bf(v1[3]);
        *(u16x8*)(&A_dst[row * 64 + p * 8]) = r;
      }
    } else {
      for (int c = 0; c < 4; ++c) {
        int g8  = c * 4 + wl;              // 8-row group 0..15
        int row = g8 * 8 + srow8;
        async_copy16(xb + (size_t)(m0 + row) * KDIM + k0 + ssrc,
                     &A_dst[g8 * 512]);    // wave-uniform base; HW adds lane*16B
      }
    }
  };
  auto stageB = [&](int c) {               // 8 waves x 56 lanes: 448 elems/copy
    if (lane < 56)
      async_copy16(krevs + w * KREV_STRIDE + W + c * 256 + (lane << 3),
                   &B_all[(c & 1) * BBUF + w * BSTRIDE]);
  };

  // prologue: tile 0 resident before first compute
  stageB(0);
  stageA(0);
  asm volatile("s_waitcnt vmcnt(0) lgkmcnt(0)" ::: "memory");
  __builtin_amdgcn_s_barrier();
  asm volatile("" ::: "memory");

  const int cmax = ct >> 1;
  for (int t = 0; ; ++t) {
    // issue next-tile stage FIRST (into buf (t+1)&1); latency hides under compute
    if (t < ct) {
      stageA(t + 1);
      if (!(t & 1) && ((t >> 1) + 1) <= cmax) stageB((t >> 1) + 1);
    }
    // compute step t from buf t&1
    const u16* Bb  = B_all + ((t >> 1) & 1) * BBUF;
    const u16* A_g = A_all + (((g << 1) | (t & 1)) << 13);
    const int  ksl = (t & 1) * 128 + g * 64;
    for (int kk = 0; kk < 2; ++kk) {
      bf16x8 af[4];
      const int p = (kk * 4 + quad) ^ (lane16 & 7);
      for (int fm = 0; fm < 4; ++fm) {
        int row = wm * 64 + fm * 16 + lane16;
        af[fm] = *(const bf16x8*)(&A_g[row * 64 + p * 8]);
      }
      bf16x8 bf[4];
      for (int fn = 0; fn < 4; ++fn)
        bf[fn] = *(const bf16x8*)(&Bb[boff[fn] + ksl + kk * 32]);
      __builtin_amdgcn_s_setprio(1);
      for (int fm = 0; fm < 4; ++fm)
        for (int fn = 0; fn < 4; ++fn)
          acc[fm][fn] = __builtin_amdgcn_mfma_f32_16x16x32_bf16(af[fm], bf[fn], acc[fm][fn], 0, 0, 0);
      __builtin_amdgcn_s_setprio(0);
    }
    if (t == ct) break;
    // one barrier per step: own stage drained, then all waves aligned
    asm volatile("s_waitcnt vmcnt(0) lgkmcnt(0)" ::: "memory");
    __builtin_amdgcn_s_barrier();
    asm volatile("" ::: "memory");
  }

  // combine: group1's partials -> group0 via LDS (2 rounds of 2 fm each)
  const int j = tid & 255;
  for (int r = 0; r < 2; ++r) {
    __syncthreads();                       // (r=0: also fences last compute reads)
    if (g == 1) {
      for (int fm2 = 0; fm2 < 2; ++fm2)
        for (int fn = 0; fn < 4; ++fn)
          ep[j * 9 + fm2 * 4 + fn] = acc[r * 2 + fm2][fn];
    }
    __syncthreads();
    if (g == 0) {
      for (int fm2 = 0; fm2 < 2; ++fm2)
        for (int fn = 0; fn < 4; ++fn)
          acc[r * 2 + fm2][fn] += ep[j * 9 + fm2 * 4 + fn];
    }
  }

  // epilogue (group 0 only): C/D layout col=lane&15, row=quad*4+r
  if (g == 0) {
    for (int fm = 0; fm < 4; ++fm) {
      int row_base = m0 + wm * 64 + fm * 16 + quad * 4;
      for (int fn = 0; fn < 4; ++fn) {
        int col = n0 + wn * 64 + fn * 16 + lane16;
        for (int r = 0; r < 4; ++r)
          out[(size_t)(row_base + r) * NDIM + col] = acc[fm][fn][r];
      }
    }
  }
}

extern "C" void kernel_launch(void* const* d_in, const int* in_sizes, int n_in,
                              void* d_out, int out_size, void* d_ws, size_t ws_size,
                              hipStream_t stream) {
  const float* x    = (const float*)d_in[0];
  const float* kern = (const float*)d_in[1];
  float* out = (float*)d_out;

  u16* krevs = (u16*)d_ws;
  u16* xb    = (u16*)((char*)d_ws + KREV_BYTES);
  const size_t need_fast = (size_t)KREV_BYTES + (size_t)MDIM * KDIM * 2;

  if (ws_size >= need_fast) {
    prep<<<4096 + 18, 256, 0, stream>>>(x, kern, xb, krevs, 4096);
    toeplitz_gemm<false><<<512, 512, 0, stream>>>(xb, krevs, out);
  } else {
    prep<<<18, 256, 0, stream>>>(x, kern, xb, krevs, 0);
    toeplitz_gemm<true><<<512, 512, 0, stream>>>(x, krevs, out);
  }
}

// Round 3
// 117.240 us; speedup vs baseline: 1.0264x; 1.0264x over previous
//
#include <hip/hip_runtime.h>
#include <hip/hip_bf16.h>

// out[b,i] = sum_{j<=i} x[b,j] * kernel[i-j]   (causal Toeplitz matmul)
// M=2048, N=K=4096. f32 in/out, bf16 MFMA compute.
//
// R8: (a) fix R7's balance bug: co-resident blocks b,b+256 now get ct pairs
// summing to 31 (33 steps/CU uniform; R7 ranged 18..48) while keeping XCD
// panel affinity (XCD x owns m-panels {x,x+8}, 2MB L2-resident; co-resident
// pair shares ONE panel). (b) break the read/MFMA convoy: counters showed
// port(3.1K) + MFMA(2.5K) ~= wall(6.1K cyc/round), i.e. zero overlap -- all
// 16 barrier-aligned waves burst 8 ds_reads then burst 16 MFMAs. Inner loop
// now rolls B-fragment reads into the MFMA stream (af x4 + 2 B preloaded,
// then {issue next B read | 4 MFMA} per fn), sched_group_barrier-pinned so
// hipcc can't re-clump; fragment liveness drops 32->28 regs (we sit at the
// 128-reg/16-wave ceiling). setprio(1) wraps each 4-MFMA cluster.

typedef unsigned short u16;
typedef __attribute__((ext_vector_type(8))) short  bf16x8;
typedef __attribute__((ext_vector_type(8))) unsigned short u16x8;
typedef __attribute__((ext_vector_type(4))) float  f32x4;

#define KDIM 4096
#define NDIM 4096
#define MDIM 2048
#define KREV_STRIDE 4608                    // elems per shifted copy
#define KREV_BYTES  (8 * KREV_STRIDE * 2)   // 73728
#define BSTRIDE 456                         // LDS B copy stride (elems); reads need [8,399)
#define BBUF    (8 * BSTRIDE)               // 3648 elems per B buffer

#define SGB __builtin_amdgcn_sched_group_barrier
#define MFMA_BF16 __builtin_amdgcn_mfma_f32_16x16x32_bf16

static __device__ inline u16 f2bf(float f) {
  unsigned u = __builtin_bit_cast(unsigned, f);
  unsigned r = u + 0x7FFFu + ((u >> 16) & 1u);
  return (u16)(r >> 16);
}

static __device__ inline void async_copy16(const void* g, void* l) {
  __builtin_amdgcn_global_load_lds((const __attribute__((address_space(1))) void*)g,
                                   (__attribute__((address_space(3))) void*)l,
                                   16, 0, 0);
}

// Fused prep: blocks [0, conv_blocks) convert x->bf16; last 18 blocks build
// 8 shifted krev copies. krevs[a][u] = krev_logical[u+a-8];
// krev_logical[t] = kern[4095-t] for t in [0,4096) else 0.
__global__ __launch_bounds__(256) void prep(const float* __restrict__ x,
                                            const float* __restrict__ kern,
                                            u16* __restrict__ xb,
                                            u16* __restrict__ krevs,
                                            int conv_blocks) {
  int kb = (int)blockIdx.x - conv_blocks;
  if (kb >= 0) {
    int u = kb * 256 + threadIdx.x;
    for (int a = 0; a < 8; ++a) {
      int t = u + a - 8;
      u16 v = 0;
      if (t >= 0 && t <= 4095) v = f2bf(kern[4095 - t]);
      krevs[a * KREV_STRIDE + u] = v;
    }
  } else {
    size_t i = ((size_t)blockIdx.x * 256 + threadIdx.x) * 8;
    const f32x4* p = (const f32x4*)(x + i);
    f32x4 v0 = p[0], v1 = p[1];
    u16x8 r;
    r[0] = f2bf(v0[0]); r[1] = f2bf(v0[1]); r[2] = f2bf(v0[2]); r[3] = f2bf(v0[3]);
    r[4] = f2bf(v1[0]); r[5] = f2bf(v1[1]); r[6] = f2bf(v1[2]); r[7] = f2bf(v1[3]);
    *(u16x8*)(xb + i) = r;
  }
}

template <bool CONV>
__global__ __launch_bounds__(512, 4) void toeplitz_gemm(const void* __restrict__ Av,
                                                        const u16* __restrict__ krevs,
                                                        float* __restrict__ out) {
  // layout: A [2 groups][2 bufs][128*64] = 32768 elems (65536 B),
  // B [2 bufs][8*456] = 7296 elems (14592 B). total 80128 B -> 2 blocks/CU.
  // Epilogue overlays (needs 36864 B).
  __shared__ __align__(16) char smem_raw[80128];
  u16*   A_all = (u16*)smem_raw;              // 4 x 8192 elems: (g<<1|buf)
  u16*   B_all = (u16*)(smem_raw + 65536);    // 2 x 3648 elems
  f32x4* ep    = (f32x4*)smem_raw;            // epilogue overlay, 9 f32x4 per slot

  const int tid  = threadIdx.x;
  const int w    = tid >> 6;        // 0..7
  const int g    = w >> 2;          // K-group 0..1
  const int wl   = w & 3;           // wave-in-group
  const int lane = tid & 63;
  const int lane16 = lane & 15;
  const int quad   = lane >> 4;
  const int wm = wl >> 1;
  const int wn = wl & 1;

  // XCD-affine, balance-correct mapping: XCD x_=b&7 owns m-panels {x_,x_+8}.
  // q=jj&31 picks the panel parity and column pair; h=jj>>5 is the dispatch
  // half. Co-resident pair (b, b+256): same mt (shared A panel), ct sum = 31
  // -> 33 steps per CU uniformly. Bijective over (mt, ct).
  const int b  = (int)blockIdx.x;
  const int x_ = b & 7;
  const int jj = b >> 3;                  // 0..63 within XCD
  const int q  = jj & 31;
  const int h  = jj >> 5;
  const int mt = x_ + 8 * (q & 1);        // m-panel 0..15
  const int ct = h ? (q >> 1) : 31 - (q >> 1);
  const int n0 = ct * 128;
  const int m0 = mt * 128;
  const int W  = 3968 - n0;               // B window base for chunk 0

  // B frag: elem j = krev_logical[s0 + k], s0 = 4095-n_g+quad*8; chunk c holds
  // krev_logical[W + c*256 + u + a - 8] at copy a elem u (u in [0,448)).
  int boff[4];
  for (int fn = 0; fn < 4; ++fn) {
    int n_g = n0 + wn * 64 + fn * 16 + lane16;
    int s0  = 4095 - n_g + quad * 8;
    int a   = s0 & 7;
    boff[fn] = a * BSTRIDE + (s0 - a + 8 - W);
  }

  f32x4 acc[4][4] = {};
  const int srow8 = lane >> 3;
  const int ssrc  = ((lane & 7) ^ srow8) * 8;   // XOR source swizzle (16B chunks)

  const u16*  xb = (const u16*)Av;
  const float* xf = (const float*)Av;

  auto stageA = [&](int t) {
    const int k0 = t * 128 + g * 64;
    u16* A_dst = A_all + (((g << 1) | (t & 1)) << 13);   // *8192
    if constexpr (CONV) {
      int j    = tid & 255;                // 256 threads per group
      int row  = j >> 1;
      int lh   = j & 1;
      for (int lc = 0; lc < 4; ++lc) {
        int l = lh * 4 + lc;
        int p = l ^ (row & 7);
        const f32x4* px = (const f32x4*)(xf + (size_t)(m0 + row) * KDIM + k0 + l * 8);
        f32x4 v0 = px[0], v1 = px[1];
        u16x8 r;
        r[0]=f2bf(v0[0]); r[1]=f2bf(v0[1]); r[2]=f2bf(v0[2]); r[3]=f2bf(v0[3]);
        r[4]=f2bf(v1[0]); r[5]=f2bf(v1[1]); r[6]=f2bf(v1[2]); r[7]=f2bf(v1[3]);
        *(u16x8*)(&A_dst[row * 64 + p * 8]) = r;
      }
    } else {
      for (int c = 0; c < 4; ++c) {
        int g8  = c * 4 + wl;              // 8-row group 0..15
        int row = g8 * 8 + srow8;
        async_copy16(xb + (size_t)(m0 + row) * KDIM + k0 + ssrc,
                     &A_dst[g8 * 512]);    // wave-uniform base; HW adds lane*16B
      }
    }
  };
  auto stageB = [&](int c) {               // 8 waves x 56 lanes: 448 elems/copy
    if (lane < 56)
      async_copy16(krevs + w * KREV_STRIDE + W + c * 256 + (lane << 3),
                   &B_all[(c & 1) * BBUF + w * BSTRIDE]);
  };

  // prologue: tile 0 resident before first compute
  stageB(0);
  stageA(0);
  asm volatile("s_waitcnt vmcnt(0) lgkmcnt(0)" ::: "memory");
  __builtin_amdgcn_s_barrier();
  asm volatile("" ::: "memory");

  const int cmax = ct >> 1;
  const u16* Arow = nullptr;
  for (int t = 0; ; ++t) {
    // issue next-tile stage FIRST (into buf (t+1)&1); latency hides under compute
    if (t < ct) {
      stageA(t + 1);
      if (!(t & 1) && ((t >> 1) + 1) <= cmax) stageB((t >> 1) + 1);
    }
    // compute step t from buf t&1; rolled read->MFMA interleave per kk.
    const u16* Bb  = B_all + ((t >> 1) & 1) * BBUF;
    const u16* A_g = A_all + (((g << 1) | (t & 1)) << 13);
    const int  ksl = (t & 1) * 128 + g * 64;
    Arow = &A_g[(wm * 64 + lane16) * 64];
#pragma unroll
    for (int kk = 0; kk < 2; ++kk) {
      const int p8 = ((kk * 4 + quad) ^ (lane16 & 7)) * 8;
      const u16* Bk = Bb + ksl + kk * 32;
      bf16x8 af0 = *(const bf16x8*)(Arow +    0 + p8);
      bf16x8 af1 = *(const bf16x8*)(Arow + 1024 + p8);
      bf16x8 af2 = *(const bf16x8*)(Arow + 2048 + p8);
      bf16x8 af3 = *(const bf16x8*)(Arow + 3072 + p8);
      bf16x8 b0  = *(const bf16x8*)(Bk + boff[0]);
      bf16x8 b1  = *(const bf16x8*)(Bk + boff[1]);
      // fn=0 (uses b0), overlapped with b2 read
      bf16x8 b2  = *(const bf16x8*)(Bk + boff[2]);
      __builtin_amdgcn_s_setprio(1);
      acc[0][0] = MFMA_BF16(af0, b0, acc[0][0], 0, 0, 0);
      acc[1][0] = MFMA_BF16(af1, b0, acc[1][0], 0, 0, 0);
      acc[2][0] = MFMA_BF16(af2, b0, acc[2][0], 0, 0, 0);
      acc[3][0] = MFMA_BF16(af3, b0, acc[3][0], 0, 0, 0);
      __builtin_amdgcn_s_setprio(0);
      // fn=1 (uses b1), overlapped with b3 read
      bf16x8 b3  = *(const bf16x8*)(Bk + boff[3]);
      __builtin_amdgcn_s_setprio(1);
      acc[0][1] = MFMA_BF16(af0, b1, acc[0][1], 0, 0, 0);
      acc[1][1] = MFMA_BF16(af1, b1, acc[1][1], 0, 0, 0);
      acc[2][1] = MFMA_BF16(af2, b1, acc[2][1], 0, 0, 0);
      acc[3][1] = MFMA_BF16(af3, b1, acc[3][1], 0, 0, 0);
      __builtin_amdgcn_s_setprio(0);
      // fn=2
      __builtin_amdgcn_s_setprio(1);
      acc[0][2] = MFMA_BF16(af0, b2, acc[0][2], 0, 0, 0);
      acc[1][2] = MFMA_BF16(af1, b2, acc[1][2], 0, 0, 0);
      acc[2][2] = MFMA_BF16(af2, b2, acc[2][2], 0, 0, 0);
      acc[3][2] = MFMA_BF16(af3, b2, acc[3][2], 0, 0, 0);
      __builtin_amdgcn_s_setprio(0);
      // fn=3
      __builtin_amdgcn_s_setprio(1);
      acc[0][3] = MFMA_BF16(af0, b3, acc[0][3], 0, 0, 0);
      acc[1][3] = MFMA_BF16(af1, b3, acc[1][3], 0, 0, 0);
      acc[2][3] = MFMA_BF16(af2, b3, acc[2][3], 0, 0, 0);
      acc[3][3] = MFMA_BF16(af3, b3, acc[3][3], 0, 0, 0);
      __builtin_amdgcn_s_setprio(0);
      // pin the interleave: 6 reads, [4 MFMA | 1 read] x2, 4 MFMA, 4 MFMA
      SGB(0x100, 6, 0);   // af0-3, b0, b1
      SGB(0x008, 4, 0);   // fn=0 MFMAs
      SGB(0x100, 1, 0);   // b2
      SGB(0x008, 4, 0);   // fn=1 MFMAs
      SGB(0x100, 1, 0);   // b3
      SGB(0x008, 4, 0);   // fn=2 MFMAs
      SGB(0x008, 4, 0);   // fn=3 MFMAs
    }
    if (t == ct) break;
    // one barrier per step: own stage drained, then all waves aligned
    asm volatile("s_waitcnt vmcnt(0) lgkmcnt(0)" ::: "memory");
    __builtin_amdgcn_s_barrier();
    asm volatile("" ::: "memory");
  }

  // combine: group1's partials -> group0 via LDS (2 rounds of 2 fm each)
  const int j = tid & 255;
  for (int r = 0; r < 2; ++r) {
    __syncthreads();                       // (r=0: also fences last compute reads)
    if (g == 1) {
      for (int fm2 = 0; fm2 < 2; ++fm2)
        for (int fn = 0; fn < 4; ++fn)
          ep[j * 9 + fm2 * 4 + fn] = acc[r * 2 + fm2][fn];
    }
    __syncthreads();
    if (g == 0) {
      for (int fm2 = 0; fm2 < 2; ++fm2)
        for (int fn = 0; fn < 4; ++fn)
          acc[r * 2 + fm2][fn] += ep[j * 9 + fm2 * 4 + fn];
    }
  }

  // epilogue (group 0 only): C/D layout col=lane&15, row=quad*4+r
  if (g == 0) {
    for (int fm = 0; fm < 4; ++fm) {
      int row_base = m0 + wm * 64 + fm * 16 + quad * 4;
      for (int fn = 0; fn < 4; ++fn) {
        int col = n0 + wn * 64 + fn * 16 + lane16;
        for (int r = 0; r < 4; ++r)
          out[(size_t)(row_base + r) * NDIM + col] = acc[fm][fn][r];
      }
    }
  }
}

extern "C" void kernel_launch(void* const* d_in, const int* in_sizes, int n_in,
                              void* d_out, int out_size, void* d_ws, size_t ws_size,
                              hipStream_t stream) {
  const float* x    = (const float*)d_in[0];
  const float* kern = (const float*)d_in[1];
  float* out = (float*)d_out;

  u16* krevs = (u16*)d_ws;
  u16* xb    = (u16*)((char*)d_ws + KREV_BYTES);
  const size_t need_fast = (size_t)KREV_BYTES + (size_t)MDIM * KDIM * 2;

  if (ws_size >= need_fast) {
    prep<<<4096 + 18, 256, 0, stream>>>(x, kern, xb, krevs, 4096);
    toeplitz_gemm<false><<<512, 512, 0, stream>>>(xb, krevs, out);
  } else {
    prep<<<18, 256, 0, stream>>>(x, kern, xb, krevs, 0);
    toeplitz_gemm<true><<<512, 512, 0, stream>>>(x, krevs, out);
  }
}